// Round 5
// baseline (560.635 us; speedup 1.0000x reference)
//
#include <hip/hip_runtime.h>
#include <stdint.h>

#define M_DIM 4096
#define K_DIM 4096
#define N_DIM 11008
#define KP    512              // 16B slots (8 fp16) per K row
#define NT    64               // K tiles of 64
#define BM    256
#define BN    256

#define QP_BYTES   (11008u * 512u * 4u)
#define XW_OFFSET  25165824u
#define XW_BYTES   (4096u * 4096u * 2u)
#define WS_NEEDED  (XW_OFFSET + XW_BYTES)

typedef __attribute__((ext_vector_type(8))) _Float16 f16x8;
typedef __attribute__((ext_vector_type(2))) _Float16 f16x2;
typedef __attribute__((ext_vector_type(4))) float    f32x4;

// ---------- pre-pass 1: qweight int32 [N][K] -> nibble-interleaved u32 [N][K/8] ----------
__global__ void pack_qw(const int* __restrict__ qw, unsigned int* __restrict__ qp) {
    int stride = gridDim.x * blockDim.x;
    for (int i = blockIdx.x * blockDim.x + threadIdx.x; i < N_DIM * KP; i += stride) {
        const int* src = qw + (size_t)i * 8;
        int4 a = *(const int4*)src;
        int4 b = *(const int4*)(src + 4);
        unsigned int w = (unsigned)a.x | ((unsigned)a.z << 4) | ((unsigned)b.x << 8) | ((unsigned)b.z << 12)
                       | ((unsigned)a.y << 16) | ((unsigned)a.w << 20) | ((unsigned)b.y << 24) | ((unsigned)b.w << 28);
        qp[i] = w;
    }
}

// ---------- pre-pass 2: x fp32 -> fp16, 16B-slot XOR-pre-swizzled within 128B groups ----------
__global__ void cvt_x(const float* __restrict__ x, uint4* __restrict__ xw) {
    int stride = gridDim.x * blockDim.x;
    for (int i = blockIdx.x * blockDim.x + threadIdx.x; i < M_DIM * KP; i += stride) {
        int m  = i >> 9;
        int sg = i & 511;
        const float* src = x + ((size_t)m << 12) + sg * 8;
        float4 f0 = *(const float4*)src;
        float4 f1 = *(const float4*)(src + 4);
        union { _Float16 h[8]; uint4 v; } pk;
        pk.h[0]=(_Float16)f0.x; pk.h[1]=(_Float16)f0.y;
        pk.h[2]=(_Float16)f0.z; pk.h[3]=(_Float16)f0.w;
        pk.h[4]=(_Float16)f1.x; pk.h[5]=(_Float16)f1.y;
        pk.h[6]=(_Float16)f1.z; pk.h[7]=(_Float16)f1.w;
        int dst = (sg & ~7) | ((sg & 7) ^ (m & 7));
        xw[((size_t)m << 9) + dst] = pk.v;
    }
}

// ---------- dequant 8 nibbles -> 4 fp16x2 ----------
__device__ __forceinline__ uint4 dq8(unsigned int w, f16x2 s2, f16x2 z2) {
    const f16x2 k1024 = {(_Float16)1024.0f, (_Float16)1024.0f};
    union { f16x2 h; unsigned int u; } p0, p1, p2, p3;
    p0.u = 0x64006400u | (w & 0x000F000Fu);
    p1.u = 0x64006400u | ((w >> 4)  & 0x000F000Fu);
    p2.u = 0x64006400u | ((w >> 8)  & 0x000F000Fu);
    p3.u = 0x64006400u | ((w >> 12) & 0x000F000Fu);
    union { f16x2 h2[4]; uint4 v; } r;
    r.h2[0] = (p0.h - k1024) * s2 + z2;
    r.h2[1] = (p1.h - k1024) * s2 + z2;
    r.h2[2] = (p2.h - k1024) * s2 + z2;
    r.h2[3] = (p3.h - k1024) * s2 + z2;
    return r.v;
}

#define MFMA16(d, va, vb) d = __builtin_amdgcn_mfma_f32_16x16x32_f16(va, vb, d, 0, 0, 0)

// ---------- main GEMM: 256x256 tile, 4-phase/K-tile pipelined, counted vmcnt ----------
__global__ __launch_bounds__(512, 2) void wq_gemm_8ph(
    const uint4*  __restrict__ xw,     // fp16 [M][512] slots, pre-swizzled
    const uint4*  __restrict__ qp4,    // packed [N][128] uint4
    const float*  __restrict__ scales, // fp32 [32][N]
    const float*  __restrict__ zeros,  // fp32 [32][N]
    const float*  __restrict__ bias,   // fp32 [N]
    float*        __restrict__ out)    // fp32 [M][N]
{
    __shared__ __align__(16) uint4 Asl[2][2048];   // [buf][row*8+slot] 64 KiB
    __shared__ __align__(16) uint4 Bsl[2][2048];   // 64 KiB

    const int tid  = threadIdx.x;
    const int lane = tid & 63;
    const int wid  = tid >> 6;
    const int wm   = wid >> 2;          // 0..1
    const int wn   = wid & 3;           // 0..3
    const int l15  = lane & 15;
    const int l4   = lane >> 4;
    const int sw   = l15 & 7;

    // XCD-aware swizzle: 688 blocks = 8*86, bijective
    int id  = blockIdx.x;
    int swz = (id & 7) * 86 + (id >> 3);
    const int n0 = (swz >> 4) * BN;     // 0..42
    const int m0 = (swz & 15) * BM;     // 0..15

    const int brow  = tid >> 1;         // 0..255
    const int bhalf = tid & 1;

    f32x4 acc[8][4] = {};

    // ---- staging helpers ----
    auto stageA = [&](int t, int h) {
        int b = t & 1;
        #pragma unroll
        for (int i = 0; i < 2; ++i) {
            int off16 = h * 1024 + i * 512 + tid;
            int row   = off16 >> 3;
            int sl    = off16 & 7;
            const uint4* gsrc = xw + (size_t)(m0 + row) * KP + t * 8 + sl;
            __builtin_amdgcn_global_load_lds(
                (const __attribute__((address_space(1))) unsigned int*)gsrc,
                (__attribute__((address_space(3))) unsigned int*)(&Asl[b][0] + off16),
                16, 0, 0);
        }
    };
    auto stageB = [&](int t, uint4 bp, float s, float z) {
        int b = t & 1;
        f16x2 s2 = {(_Float16)s, (_Float16)s};
        f16x2 z2 = {(_Float16)z, (_Float16)z};
        unsigned int wv[4] = {bp.x, bp.y, bp.z, bp.w};
        #pragma unroll
        for (int j = 0; j < 4; ++j) {
            int sl = (bhalf * 4 + j) ^ (brow & 7);
            Bsl[b][brow * 8 + sl] = dq8(wv[j], s2, z2);
        }
    };

    // ---- prologue: fully stage tile 0, preload tile-1 B inputs ----
    stageA(0, 0); stageA(0, 1);
    uint4 bp0 = qp4[(size_t)(n0 + brow) * 128 + bhalf];
    float s0  = scales[n0 + brow];
    float z0  = zeros [n0 + brow];
    asm volatile("s_waitcnt vmcnt(0)" ::: "memory");
    __builtin_amdgcn_sched_barrier(0);
    stageB(0, bp0, s0, z0);
    uint4 bp_n = qp4[(size_t)(n0 + brow) * 128 + 2 + bhalf];   // tile 1
    float s_n  = scales[n0 + brow];                            // g = 0
    float z_n  = zeros [n0 + brow];
    asm volatile("s_waitcnt lgkmcnt(0)" ::: "memory");
    __builtin_amdgcn_sched_barrier(0);
    __builtin_amdgcn_s_barrier();

    for (int u = 0; u < NT; ++u) {
        const int cur = u & 1;
        const int t   = u + 1;
        const bool st = (t < NT);
        const uint4* Ac = &Asl[cur][0];
        const uint4* Bc = &Bsl[cur][0];

        f16x8 aA[4][2], aB[4][2], b[2][2];

        // ================= phase 0 =================
        if (st) stageA(t, 0);
        #pragma unroll
        for (int m = 0; m < 4; ++m)
            #pragma unroll
            for (int ks = 0; ks < 2; ++ks)
                aA[m][ks] = *(const f16x8*)(Ac + (wm * 128 + m * 16 + l15) * 8 + ((ks * 4 + l4) ^ sw));
        #pragma unroll
        for (int n = 0; n < 2; ++n)
            #pragma unroll
            for (int ks = 0; ks < 2; ++ks)
                b[n][ks] = *(const f16x8*)(Bc + (wn * 64 + n * 16 + l15) * 8 + ((ks * 4 + l4) ^ sw));
        __builtin_amdgcn_s_barrier();
        asm volatile("s_waitcnt lgkmcnt(0)" ::: "memory");
        __builtin_amdgcn_sched_barrier(0);
        __builtin_amdgcn_s_setprio(1);
        #pragma unroll
        for (int m = 0; m < 4; ++m)
            #pragma unroll
            for (int n = 0; n < 2; ++n)
                #pragma unroll
                for (int ks = 0; ks < 2; ++ks)
                    MFMA16(acc[m][n], aA[m][ks], b[n][ks]);
        __builtin_amdgcn_s_setprio(0);
        __builtin_amdgcn_s_barrier();

        // ================= phase 1 =================
        if (st) stageA(t, 1);
        #pragma unroll
        for (int m = 0; m < 4; ++m)
            #pragma unroll
            for (int ks = 0; ks < 2; ++ks)
                aB[m][ks] = *(const f16x8*)(Ac + (wm * 128 + (m + 4) * 16 + l15) * 8 + ((ks * 4 + l4) ^ sw));
        __builtin_amdgcn_s_barrier();
        asm volatile("s_waitcnt lgkmcnt(0)" ::: "memory");
        __builtin_amdgcn_sched_barrier(0);
        __builtin_amdgcn_s_setprio(1);
        #pragma unroll
        for (int m = 0; m < 4; ++m)
            #pragma unroll
            for (int n = 0; n < 2; ++n)
                #pragma unroll
                for (int ks = 0; ks < 2; ++ks)
                    MFMA16(acc[m + 4][n], aB[m][ks], b[n][ks]);
        __builtin_amdgcn_s_setprio(0);
        __builtin_amdgcn_s_barrier();

        // ================= phase 2 =================
        if (st) {
            asm volatile("s_waitcnt vmcnt(4)" ::: "memory");   // bp_n/s_n/z_n landed; A(t) may fly
            __builtin_amdgcn_sched_barrier(0);
            stageB(t, bp_n, s_n, z_n);
        }
        #pragma unroll
        for (int n = 0; n < 2; ++n)
            #pragma unroll
            for (int ks = 0; ks < 2; ++ks)
                b[n][ks] = *(const f16x8*)(Bc + (wn * 64 + (n + 2) * 16 + l15) * 8 + ((ks * 4 + l4) ^ sw));
        __builtin_amdgcn_s_barrier();
        asm volatile("s_waitcnt lgkmcnt(0)" ::: "memory");
        __builtin_amdgcn_sched_barrier(0);
        __builtin_amdgcn_s_setprio(1);
        #pragma unroll
        for (int m = 0; m < 4; ++m)
            #pragma unroll
            for (int n = 0; n < 2; ++n)
                #pragma unroll
                for (int ks = 0; ks < 2; ++ks)
                    MFMA16(acc[m + 4][n + 2], aB[m][ks], b[n][ks]);
        __builtin_amdgcn_s_setprio(0);
        __builtin_amdgcn_s_barrier();

        // ================= phase 3 =================
        if (t + 1 < NT) {
            int g2 = (t + 1) >> 1;
            bp_n = qp4[(size_t)(n0 + brow) * 128 + (t + 1) * 2 + bhalf];
            s_n  = scales[(size_t)g2 * N_DIM + n0 + brow];
            z_n  = zeros [(size_t)g2 * N_DIM + n0 + brow];
            asm volatile("s_waitcnt vmcnt(3)" ::: "memory");   // A(t) landed; {bp,s,z} fly
            __builtin_amdgcn_sched_barrier(0);
        } else {
            asm volatile("s_waitcnt vmcnt(0)" ::: "memory");   // epilogue drain (last tiles)
            __builtin_amdgcn_sched_barrier(0);
        }
        __builtin_amdgcn_s_barrier();
        asm volatile("s_waitcnt lgkmcnt(0)" ::: "memory");
        __builtin_amdgcn_sched_barrier(0);
        __builtin_amdgcn_s_setprio(1);
        #pragma unroll
        for (int m = 0; m < 4; ++m)
            #pragma unroll
            for (int n = 0; n < 2; ++n)
                #pragma unroll
                for (int ks = 0; ks < 2; ++ks)
                    MFMA16(acc[m][n + 2], aA[m][ks], b[n][ks]);
        __builtin_amdgcn_s_setprio(0);
        __builtin_amdgcn_s_barrier();
    }

    // ---- epilogue ----
    #pragma unroll
    for (int nf = 0; nf < 4; ++nf) {
        int col = n0 + wn * 64 + nf * 16 + l15;
        float bv = bias[col];
        #pragma unroll
        for (int mf = 0; mf < 8; ++mf) {
            int rbase = m0 + wm * 128 + mf * 16 + l4 * 4;
            #pragma unroll
            for (int j = 0; j < 4; ++j)
                out[(size_t)(rbase + j) * N_DIM + col] = acc[mf][nf][j] + bv;
        }
    }
}

// ---------- fallback (round-3 proven kernel) if ws too small ----------
typedef __attribute__((ext_vector_type(8))) _Float16 f16x8_t;
__global__ __launch_bounds__(256, 2) void wq_gemm_fb(
    const float* __restrict__ x, const int* __restrict__ qw,
    const float* __restrict__ scales, const float* __restrict__ zeros,
    const float* __restrict__ bias, float* __restrict__ out)
{
    __shared__ __align__(16) _Float16 As[128 * 64];
    __shared__ __align__(16) _Float16 Bs[128 * 64];
    const int tid = threadIdx.x, lane = tid & 63, wid = tid >> 6;
    const int wm = wid >> 1, wn = wid & 1, l15 = lane & 15, l4 = lane >> 4;
    const int m0 = blockIdx.y * 128, n0 = blockIdx.x * 128;
    f32x4 acc[4][4] = {};
    for (int kt = 0; kt < K_DIM / 64; ++kt) {
        const int k0 = kt * 64;
        #pragma unroll
        for (int i = 0; i < 4; ++i) {
            int ci = i * 256 + tid, row = ci >> 3, col = (ci & 7) * 8;
            const float* src = x + (size_t)(m0 + row) * K_DIM + k0 + col;
            float4 f0 = *(const float4*)src; float4 f1 = *(const float4*)(src + 4);
            union { _Float16 h[8]; uint4 v; } pk;
            pk.h[0]=(_Float16)f0.x; pk.h[1]=(_Float16)f0.y; pk.h[2]=(_Float16)f0.z; pk.h[3]=(_Float16)f0.w;
            pk.h[4]=(_Float16)f1.x; pk.h[5]=(_Float16)f1.y; pk.h[6]=(_Float16)f1.z; pk.h[7]=(_Float16)f1.w;
            *(uint4*)(As + ci * 8) = pk.v;
        }
        const int g = k0 >> 7;
        #pragma unroll
        for (int i = 0; i < 4; ++i) {
            int ci = i * 256 + tid, nl = ci >> 3, kc = (ci & 7) * 8;
            const int* qrow = qw + (size_t)(n0 + nl) * K_DIM + k0 + kc;
            int4 q0 = *(const int4*)qrow; int4 q1 = *(const int4*)(qrow + 4);
            float s = scales[(size_t)g * N_DIM + n0 + nl];
            float z = zeros [(size_t)g * N_DIM + n0 + nl];
            union { _Float16 h[8]; uint4 v; } pk;
            pk.h[0]=(_Float16)((float)q0.x*s+z); pk.h[1]=(_Float16)((float)q0.y*s+z);
            pk.h[2]=(_Float16)((float)q0.z*s+z); pk.h[3]=(_Float16)((float)q0.w*s+z);
            pk.h[4]=(_Float16)((float)q1.x*s+z); pk.h[5]=(_Float16)((float)q1.y*s+z);
            pk.h[6]=(_Float16)((float)q1.z*s+z); pk.h[7]=(_Float16)((float)q1.w*s+z);
            *(uint4*)(Bs + ci * 8) = pk.v;
        }
        __syncthreads();
        #pragma unroll
        for (int ks = 0; ks < 2; ++ks) {
            f16x8 a[4], b[4];
            #pragma unroll
            for (int m = 0; m < 4; ++m)
                a[m] = *(const f16x8*)(As + (wm*64 + m*16 + l15) * 64 + ks*32 + l4*8);
            #pragma unroll
            for (int n = 0; n < 4; ++n)
                b[n] = *(const f16x8*)(Bs + (wn*64 + n*16 + l15) * 64 + ks*32 + l4*8);
            #pragma unroll
            for (int m = 0; m < 4; ++m)
                #pragma unroll
                for (int n = 0; n < 4; ++n)
                    MFMA16(acc[m][n], a[m], b[n]);
        }
        __syncthreads();
    }
    #pragma unroll
    for (int n = 0; n < 4; ++n) {
        int col = n0 + wn * 64 + n * 16 + l15;
        float bv = bias[col];
        #pragma unroll
        for (int m = 0; m < 4; ++m) {
            int rbase = m0 + wm * 64 + m * 16 + l4 * 4;
            #pragma unroll
            for (int j = 0; j < 4; ++j)
                out[(size_t)(rbase + j) * N_DIM + col] = acc[m][n][j] + bv;
        }
    }
}

extern "C" void kernel_launch(void* const* d_in, const int* in_sizes, int n_in,
                              void* d_out, int out_size, void* d_ws, size_t ws_size,
                              hipStream_t stream) {
    const float* x  = (const float*)d_in[0];
    const int*   qw = (const int*)d_in[1];
    const float* sc = (const float*)d_in[2];
    const float* zr = (const float*)d_in[3];
    const float* bi = (const float*)d_in[4];
    float* o = (float*)d_out;

    if (ws_size >= WS_NEEDED) {
        unsigned int* qp = (unsigned int*)d_ws;
        uint4* xw = (uint4*)((char*)d_ws + XW_OFFSET);
        pack_qw<<<2048, 256, 0, stream>>>(qw, qp);
        cvt_x  <<<2048, 256, 0, stream>>>(x, xw);
        wq_gemm_8ph<<<dim3(688), dim3(512), 0, stream>>>((const uint4*)xw, (const uint4*)qp, sc, zr, bi, o);
    } else {
        dim3 grid(N_DIM / 128, M_DIM / 128);
        wq_gemm_fb<<<grid, dim3(256), 0, stream>>>(x, qw, sc, zr, bi, o);
    }
}